// Round 2
// 971.887 us; speedup vs baseline: 1.1816x; 1.1816x over previous
//
#include <hip/hip_runtime.h>

// Drifter: B=1048576 trajectories, T=101 (t = 0,20,...,2000), FS_ORDER=8.
// x_{n+1} = x_n + (sum_f sin(f x)sw[f] + cos(f x)cw[f]) * 20
// Outputs (concatenated): t_mesh [B,101], xt [B,101] (wrapped to (-pi,pi]).
// t_sample is unused by the reference outputs.
//
// V2b: V2 with native ext_vector float4 for the nontemporal builtin
//     (HIP_vector_type float4 is rejected by __builtin_nontemporal_store).

#define B_TOTAL   1048576
#define T_STEPS   101
#define FS        8
#define DT_F      20.0f
#define CHUNK     32
#define LDSTR     (CHUNK + 1)   // +1 pad: stride 33 == 1 mod 32 -> conflict-free writes
#define PI_F      3.14159265358979323846f
#define TWO_PI_F  6.28318530717958647692f
#define INV_2PI_F 0.15915494309189533577f

typedef float f4 __attribute__((ext_vector_type(4)));

__global__ __launch_bounds__(256) void drifter_kernel(
    const float* __restrict__ x0,
    const float* __restrict__ sw,
    const float* __restrict__ cw,
    float* __restrict__ out_tmesh,
    float* __restrict__ out_xt)
{
    __shared__ float lds[256 * LDSTR];

    const int tid = threadIdx.x;
    const int b   = blockIdx.x * 256 + tid;
    const size_t rowbase = (size_t)blockIdx.x * (256 * T_STEPS);  // 25856 floats, 16B-aligned

    // issue the x0 load first; latency hides under the t_mesh burst
    float x = x0[b];

    // weights: wave-uniform constant-index loads -> scalar loads, once
    float swr[FS], cwr[FS];
#pragma unroll
    for (int f = 0; f < FS; ++f) { swr[f] = sw[f]; cwr[f] = cw[f]; }

    // ---- t_mesh: dedicated fully-coalesced nontemporal float4 burst ----
    // Block region = 25856 floats = 6464 float4 (region start is 16B-aligned).
    // 25 iters x 256 threads x float4 = 25600 floats, then 256-float tail.
    // These stores are fire-and-forget: they drain while the ODE compute runs.
    {
        f4* tm = (f4*)(out_tmesh + rowbase);
        int col = (tid * 4) % T_STEPS;          // compile-time magic div
#pragma unroll
        for (int it = 0; it < 25; ++it) {
            int c0 = col;
            int c1 = c0 + 1; if (c1 >= T_STEPS) c1 -= T_STEPS;
            int c2 = c1 + 1; if (c2 >= T_STEPS) c2 -= T_STEPS;
            int c3 = c2 + 1; if (c3 >= T_STEPS) c3 -= T_STEPS;
            f4 v = { DT_F * (float)c0, DT_F * (float)c1,
                     DT_F * (float)c2, DT_F * (float)c3 };
            __builtin_nontemporal_store(v, tm + it * 256 + tid);
            col += 14;                           // 1024 % 101 == 14
            if (col >= T_STEPS) col -= T_STEPS;
        }
        if (tid < 64) {                          // tail: floats [25600, 25856)
            const int base = 25600 + tid * 4;
            int c0 = base % T_STEPS;
            int c1 = c0 + 1; if (c1 >= T_STEPS) c1 -= T_STEPS;
            int c2 = c1 + 1; if (c2 >= T_STEPS) c2 -= T_STEPS;
            int c3 = c2 + 1; if (c3 >= T_STEPS) c3 -= T_STEPS;
            f4 v = { DT_F * (float)c0, DT_F * (float)c1,
                     DT_F * (float)c2, DT_F * (float)c3 };
            __builtin_nontemporal_store(v, tm + 6400 + tid);
        }
    }

    const int q  = tid & 7;    // which 4-col group within a 32-col chunk
    const int r0 = tid >> 3;   // 0..31
    float* xtb = out_xt + rowbase;

#pragma unroll
    for (int chunk = 0; chunk < 4; ++chunk) {
        const int cbase = chunk * CHUNK;
        const int csize = (T_STEPS - cbase) < CHUNK ? (T_STEPS - cbase) : CHUNK;

        // ---- compute csize trajectory values into LDS (bit-identical to V1) ----
        for (int c = 0; c < csize; ++c) {
            // store wrapped x at global time index j = cbase + c
            float v = x + PI_F;
            // JAX/numpy mod semantics: result in [0, 2pi)
            float w = v - floorf(v * INV_2PI_F) * TWO_PI_F - PI_F;
            lds[tid * LDSTR + c] = w;

            if (cbase + c < T_STEPS - 1) {       // 100 Euler steps total
                float s1 = __sinf(x);
                float c1 = __cosf(x);
                float tc = 2.0f * c1;
                // f=0: sin term 0, cos term cw[0]
                float acc  = cwr[0] + s1 * swr[1] + c1 * cwr[1];
                float skm1 = 0.0f, ckm1 = 1.0f;  // k=0
                float sk = s1, ck = c1;          // k=1
#pragma unroll
                for (int f = 2; f < FS; ++f) {   // Chebyshev recurrence
                    float sn = tc * sk - skm1;
                    float cn = tc * ck - ckm1;
                    skm1 = sk; ckm1 = ck;
                    sk = sn;   ck = cn;
                    acc += sn * swr[f] + cn * cwr[f];
                }
                x += acc * DT_F;
            }
        }
        __syncthreads();

        // ---- coalesced transpose writeback, 4 floats per thread per store ----
        // thread -> (row r0 + 32*i, cols cbase + 4q .. +3): 4 consecutive dword
        // stores with align 4 -> LSV merges to global_store_dwordx4.
        // LDS read lanes: bank = (r + 4q + j) mod 32 -> 2-way aliasing (free).
        if (chunk < 3) {
#pragma unroll
            for (int i = 0; i < 8; ++i) {
                const int r = r0 + (i << 5);
                const float* lp = &lds[r * LDSTR + (q << 2)];
                const float v0 = lp[0], v1 = lp[1], v2 = lp[2], v3 = lp[3];
                float* p = xtb + (size_t)r * T_STEPS + (cbase + (q << 2));
                p[0] = v0; p[1] = v1; p[2] = v2; p[3] = v3;
            }
        } else {
            // tail chunk: cols 96..100 (csize = 5)
#pragma unroll
            for (int i = 0; i < 8; ++i) {
                const int r = r0 + (i << 5);
                const float* lp = &lds[r * LDSTR];
                float* p = xtb + (size_t)r * T_STEPS + 96;
                if (q == 0) {
                    const float v0 = lp[0], v1 = lp[1], v2 = lp[2], v3 = lp[3];
                    p[0] = v0; p[1] = v1; p[2] = v2; p[3] = v3;
                } else if (q == 1) {
                    p[4] = lp[4];
                }
            }
        }
        __syncthreads();
    }
}

extern "C" void kernel_launch(void* const* d_in, const int* in_sizes, int n_in,
                              void* d_out, int out_size, void* d_ws, size_t ws_size,
                              hipStream_t stream) {
    const float* x0 = (const float*)d_in[0];   // [B] fp32
    const float* sw = (const float*)d_in[1];   // [8] fp32
    const float* cw = (const float*)d_in[2];   // [8] fp32
    // d_in[3] = t_sample (int32) -- unused by reference outputs

    float* out = (float*)d_out;
    const long long half = (long long)B_TOTAL * T_STEPS;  // t_mesh first, xt second

    drifter_kernel<<<B_TOTAL / 256, 256, 0, stream>>>(x0, sw, cw, out, out + half);
}

// Round 3
// 963.516 us; speedup vs baseline: 1.1919x; 1.0087x over previous
//
#include <hip/hip_runtime.h>

// Drifter: B=1048576 trajectories, T=101 (t = 0,20,...,2000), FS_ORDER=8.
// x_{n+1} = x_n + (sum_f sin(f x)sw[f] + cos(f x)cw[f]) * 20
// Outputs (concatenated): t_mesh [B,101], xt [B,101] (wrapped to (-pi,pi]).
// t_sample is unused by the reference outputs.
//
// V3: ZERO barriers. Transpose is wave-private (each wave owns 64 rows and
//     its own LDS slab) -> no __syncthreads -> the compiler never emits
//     s_waitcnt vmcnt(0), so global stores (t_mesh burst + xt writeback)
//     drain asynchronously under later compute instead of piling up at
//     barrier epochs. Cross-lane LDS visibility within a wave is guaranteed
//     by in-order per-wave DS processing; asm memory fences stop compiler
//     reordering. Arithmetic bit-identical to V1/V2 (absmax preserved).

#define B_TOTAL   1048576
#define T_STEPS   101
#define FS        8
#define DT_F      20.0f
#define CHUNK     32
#define LDSTR     (CHUNK + 1)   // stride 33 == 1 mod 32 -> conflict-free
#define PI_F      3.14159265358979323846f
#define TWO_PI_F  6.28318530717958647692f
#define INV_2PI_F 0.15915494309189533577f

typedef float f4 __attribute__((ext_vector_type(4)));

__global__ __launch_bounds__(256) void drifter_kernel(
    const float* __restrict__ x0,
    const float* __restrict__ sw,
    const float* __restrict__ cw,
    float* __restrict__ out_tmesh,
    float* __restrict__ out_xt)
{
    __shared__ float lds[256 * LDSTR];

    const int tid = threadIdx.x;
    const int b   = blockIdx.x * 256 + tid;
    const size_t rowbase = (size_t)blockIdx.x * (256 * T_STEPS);  // 25856 floats, 16B-aligned

    // issue the x0 load first; latency hides under the t_mesh burst
    float x = x0[b];

    // weights: wave-uniform constant-index loads -> scalar loads, once
    float swr[FS], cwr[FS];
#pragma unroll
    for (int f = 0; f < FS; ++f) { swr[f] = sw[f]; cwr[f] = cw[f]; }

    // ---- t_mesh: dedicated fully-coalesced nontemporal float4 burst ----
    // 6464 float4 per block region (16B-aligned). Fire-and-forget: with no
    // barriers anywhere, these drain under the whole ODE compute phase.
    {
        f4* tm = (f4*)(out_tmesh + rowbase);
        int col = (tid * 4) % T_STEPS;
#pragma unroll
        for (int it = 0; it < 25; ++it) {
            int c0 = col;
            int c1 = c0 + 1; if (c1 >= T_STEPS) c1 -= T_STEPS;
            int c2 = c1 + 1; if (c2 >= T_STEPS) c2 -= T_STEPS;
            int c3 = c2 + 1; if (c3 >= T_STEPS) c3 -= T_STEPS;
            f4 v = { DT_F * (float)c0, DT_F * (float)c1,
                     DT_F * (float)c2, DT_F * (float)c3 };
            __builtin_nontemporal_store(v, tm + it * 256 + tid);
            col += 14;                           // 1024 % 101 == 14
            if (col >= T_STEPS) col -= T_STEPS;
        }
        if (tid < 64) {                          // tail: floats [25600, 25856)
            const int base = 25600 + tid * 4;
            int c0 = base % T_STEPS;
            int c1 = c0 + 1; if (c1 >= T_STEPS) c1 -= T_STEPS;
            int c2 = c1 + 1; if (c2 >= T_STEPS) c2 -= T_STEPS;
            int c3 = c2 + 1; if (c3 >= T_STEPS) c3 -= T_STEPS;
            f4 v = { DT_F * (float)c0, DT_F * (float)c1,
                     DT_F * (float)c2, DT_F * (float)c3 };
            __builtin_nontemporal_store(v, tm + 6400 + tid);
        }
    }

    // wave-private transpose geometry: wave w owns rows [64w, 64w+64)
    const int lane  = tid & 63;
    const int wbase = tid & ~63;      // 64 * wave_id (WG-relative row base)
    const int q     = lane & 7;       // 4-col group within the 32-col chunk
    const int rl    = lane >> 3;      // 0..7
    float* xtb = out_xt + rowbase;

#pragma unroll
    for (int chunk = 0; chunk < 4; ++chunk) {
        const int cbase = chunk * CHUNK;
        const int csize = (T_STEPS - cbase) < CHUNK ? (T_STEPS - cbase) : CHUNK;

        // ---- compute csize trajectory values into this wave's LDS slab ----
        for (int c = 0; c < csize; ++c) {
            // wrapped x at global time index j = cbase + c
            float v = x + PI_F;
            // JAX/numpy mod semantics: result in [0, 2pi)
            float w = v - floorf(v * INV_2PI_F) * TWO_PI_F - PI_F;
            lds[tid * LDSTR + c] = w;           // bank (tid + c) % 32: 2-way, free

            if (cbase + c < T_STEPS - 1) {      // 100 Euler steps total
                float s1 = __sinf(x);
                float c1 = __cosf(x);
                float tc = 2.0f * c1;
                // f=0: sin term 0, cos term cw[0]
                float acc  = cwr[0] + s1 * swr[1] + c1 * cwr[1];
                float skm1 = 0.0f, ckm1 = 1.0f; // k=0
                float sk = s1, ck = c1;         // k=1
#pragma unroll
                for (int f = 2; f < FS; ++f) {  // Chebyshev recurrence
                    float sn = tc * sk - skm1;
                    float cn = tc * ck - ckm1;
                    skm1 = sk; ckm1 = ck;
                    sk = sn;   ck = cn;
                    acc += sn * swr[f] + cn * cwr[f];
                }
                x += acc * DT_F;
            }
        }

        // compiler fence: no hardware barrier. In-order per-wave DS processing
        // makes lane X's ds_write visible to this wave's later ds_read.
        asm volatile("" ::: "memory");

        // ---- wave-private transpose writeback ----
        // lane -> rows (wbase + rl + 8i), cols cbase + 4q .. +3.
        // LDS read banks: (rl + 8i + 4q + j) % 32 -> ~2-way, free.
        // Global: 8 x 128B segments per wave instruction (as V2).
        if (chunk < 3) {
#pragma unroll
            for (int i = 0; i < 8; ++i) {
                const int r = wbase + rl + (i << 3);
                const float* lp = &lds[r * LDSTR + (q << 2)];
                const float v0 = lp[0], v1 = lp[1], v2 = lp[2], v3 = lp[3];
                float* p = xtb + (size_t)r * T_STEPS + (cbase + (q << 2));
                p[0] = v0; p[1] = v1; p[2] = v2; p[3] = v3;
            }
        } else {
            // tail chunk: cols 96..100 (csize = 5)
#pragma unroll
            for (int i = 0; i < 8; ++i) {
                const int r = wbase + rl + (i << 3);
                const float* lp = &lds[r * LDSTR];
                float* p = xtb + (size_t)r * T_STEPS + 96;
                if (q == 0) {
                    const float v0 = lp[0], v1 = lp[1], v2 = lp[2], v3 = lp[3];
                    p[0] = v0; p[1] = v1; p[2] = v2; p[3] = v3;
                } else if (q == 1) {
                    p[4] = lp[4];
                }
            }
        }

        // fence before next chunk's compute overwrites the slab (WAR across lanes)
        asm volatile("" ::: "memory");
    }
}

extern "C" void kernel_launch(void* const* d_in, const int* in_sizes, int n_in,
                              void* d_out, int out_size, void* d_ws, size_t ws_size,
                              hipStream_t stream) {
    const float* x0 = (const float*)d_in[0];   // [B] fp32
    const float* sw = (const float*)d_in[1];   // [8] fp32
    const float* cw = (const float*)d_in[2];   // [8] fp32
    // d_in[3] = t_sample (int32) -- unused by reference outputs

    float* out = (float*)d_out;
    const long long half = (long long)B_TOTAL * T_STEPS;  // t_mesh first, xt second

    drifter_kernel<<<B_TOTAL / 256, 256, 0, stream>>>(x0, sw, cw, out, out + half);
}